// Round 1
// baseline (487.354 us; speedup 1.0000x reference)
//
#include <hip/hip_runtime.h>
#include <cstdint>

// ---------------- CSR build ----------------

__global__ void count_edges(const int* __restrict__ dst, int* __restrict__ cnt, int ne) {
  int e = blockIdx.x * blockDim.x + threadIdx.x;
  if (e < ne) atomicAdd(&cnt[dst[e]], 1);
}

__global__ void compute_dinv(const int* __restrict__ cnt, float* __restrict__ dinv, int n) {
  int i = blockIdx.x * blockDim.x + threadIdx.x;
  if (i < n) dinv[i] = rsqrtf((float)(cnt[i] + 1));  // +1 self-loop; always > 0
}

__global__ void scan_block(const int* __restrict__ cnt, int* __restrict__ part,
                           int* __restrict__ bsum, int n) {
  __shared__ int s[1024];
  int i = blockIdx.x * 1024 + threadIdx.x;
  int v = (i < n) ? cnt[i] : 0;
  s[threadIdx.x] = v;
  __syncthreads();
  for (int off = 1; off < 1024; off <<= 1) {
    int t = (threadIdx.x >= (unsigned)off) ? s[threadIdx.x - off] : 0;
    __syncthreads();
    s[threadIdx.x] += t;
    __syncthreads();
  }
  if (i < n) part[i] = s[threadIdx.x] - v;           // exclusive within block
  if (threadIdx.x == 1023) bsum[blockIdx.x] = s[1023];
}

__global__ void scan_bsum(int* __restrict__ bsum, int nb) {  // nb <= 64
  int lane = threadIdx.x;
  int v = (lane < nb) ? bsum[lane] : 0;
  int orig = v;
  for (int off = 1; off < 64; off <<= 1) {
    int t = __shfl_up(v, off);
    if (lane >= off) v += t;
  }
  if (lane < nb) bsum[lane] = v - orig;              // exclusive block offsets
}

__global__ void finalize_rowptr(const int* __restrict__ part, const int* __restrict__ bsum,
                                int* __restrict__ row_ptr, int n, int total) {
  int i = blockIdx.x * blockDim.x + threadIdx.x;
  if (i < n) row_ptr[i] = part[i] + bsum[i >> 10];
  if (i == n) row_ptr[n] = total;
}

__global__ void fill_csr(const int* __restrict__ src, const int* __restrict__ dst,
                         int* __restrict__ cursor, int* __restrict__ col, int ne) {
  int e = blockIdx.x * blockDim.x + threadIdx.x;
  if (e < ne) {
    int d = dst[e];
    int pos = atomicAdd(&cursor[d], 1);
    col[pos] = src[e];
  }
}

// ---------------- GEMM (fp32, 128-wide weights) fused with dinv pre-scale ----------------
// out[i][f] = (sum_k in[i][k] * W[k][f]) * dinv[i]
// Block: 256 threads -> 64 rows x 128 cols. Thread tile: 4 rows x 8 cols
// (cols cg*4..cg*4+3 and 64+cg*4..64+cg*4+3 to keep LDS b128 reads 2-way max).

__global__ __launch_bounds__(256) void gemm_scale(const float* __restrict__ in,
                                                  const float* __restrict__ W,
                                                  const float* __restrict__ dinv,
                                                  float* __restrict__ out, int nrows) {
  __shared__ float ws[16][128];
  __shared__ float xs[64][17];
  int row0 = blockIdx.x * 64;
  int tid = threadIdx.x;
  int rg = tid >> 4;   // 0..15 -> rows rg*4..rg*4+3
  int cg = tid & 15;   // 0..15 -> cols cg*4 & 64+cg*4

  float acc[4][8] = {{0.f}};

  for (int k0 = 0; k0 < 128; k0 += 16) {
    // stage W chunk: 16x128 floats, 8 per thread
    {
      int idx = tid * 8;
      int kk = idx >> 7;
      int f = idx & 127;
      float4 a = *(const float4*)&W[(size_t)(k0 + kk) * 128 + f];
      float4 b = *(const float4*)&W[(size_t)(k0 + kk) * 128 + f + 4];
      *(float4*)&ws[kk][f] = a;
      *(float4*)&ws[kk][f + 4] = b;
    }
    // stage x chunk: 64x16 floats, 4 per thread
    {
      int idx = tid * 4;
      int r = idx >> 4;
      int kk = idx & 15;
      int grow = row0 + r;
      float4 v = make_float4(0.f, 0.f, 0.f, 0.f);
      if (grow < nrows) v = *(const float4*)&in[(size_t)grow * 128 + k0 + kk];
      xs[r][kk] = v.x; xs[r][kk + 1] = v.y; xs[r][kk + 2] = v.z; xs[r][kk + 3] = v.w;
    }
    __syncthreads();
#pragma unroll
    for (int kk = 0; kk < 16; ++kk) {
      float b0[8];
      *(float4*)&b0[0] = *(const float4*)&ws[kk][cg * 4];
      *(float4*)&b0[4] = *(const float4*)&ws[kk][64 + cg * 4];
      float a0 = xs[rg * 4 + 0][kk];
      float a1 = xs[rg * 4 + 1][kk];
      float a2 = xs[rg * 4 + 2][kk];
      float a3 = xs[rg * 4 + 3][kk];
#pragma unroll
      for (int j = 0; j < 8; ++j) {
        acc[0][j] += a0 * b0[j];
        acc[1][j] += a1 * b0[j];
        acc[2][j] += a2 * b0[j];
        acc[3][j] += a3 * b0[j];
      }
    }
    __syncthreads();
  }

#pragma unroll
  for (int r = 0; r < 4; ++r) {
    int grow = row0 + rg * 4 + r;
    if (grow < nrows) {
      float s = dinv[grow];
      float4 o0 = make_float4(acc[r][0] * s, acc[r][1] * s, acc[r][2] * s, acc[r][3] * s);
      float4 o1 = make_float4(acc[r][4] * s, acc[r][5] * s, acc[r][6] * s, acc[r][7] * s);
      *(float4*)&out[(size_t)grow * 128 + cg * 4] = o0;
      *(float4*)&out[(size_t)grow * 128 + 64 + cg * 4] = o1;
    }
  }
}

// ---------------- Aggregation (gather over CSR) + post-scale + bias + relu ----------------
// One wave per node; lane holds features 2*lane, 2*lane+1 as float2.

__global__ __launch_bounds__(256) void aggregate(const float* __restrict__ hs,
                                                 const int* __restrict__ row_ptr,
                                                 const int* __restrict__ col,
                                                 const float* __restrict__ dinv,
                                                 const float* __restrict__ bias,
                                                 float* __restrict__ out, int n) {
  int wid = (blockIdx.x * blockDim.x + threadIdx.x) >> 6;
  int lane = threadIdx.x & 63;
  if (wid >= n) return;
  int i = wid;
  int start = row_ptr[i];
  int end = row_ptr[i + 1];

  float2 acc = ((const float2*)&hs[(size_t)i * 128])[lane];  // self-loop term

  int e = start;
  for (; e + 4 <= end; e += 4) {
    int s0 = col[e + 0];
    int s1 = col[e + 1];
    int s2 = col[e + 2];
    int s3 = col[e + 3];
    float2 v0 = ((const float2*)&hs[(size_t)s0 * 128])[lane];
    float2 v1 = ((const float2*)&hs[(size_t)s1 * 128])[lane];
    float2 v2 = ((const float2*)&hs[(size_t)s2 * 128])[lane];
    float2 v3 = ((const float2*)&hs[(size_t)s3 * 128])[lane];
    acc.x += (v0.x + v1.x) + (v2.x + v3.x);
    acc.y += (v0.y + v1.y) + (v2.y + v3.y);
  }
  for (; e < end; ++e) {
    int s0 = col[e];
    float2 v0 = ((const float2*)&hs[(size_t)s0 * 128])[lane];
    acc.x += v0.x;
    acc.y += v0.y;
  }

  float d = dinv[i];
  float2 b = ((const float2*)bias)[lane];
  float ox = fmaxf(acc.x * d + b.x, 0.f);
  float oy = fmaxf(acc.y * d + b.y, 0.f);
  ((float2*)&out[(size_t)i * 128])[lane] = make_float2(ox, oy);
}

// ---------------- Final projection: out[i] = dot(h[i], Wc) + bc ----------------

__global__ __launch_bounds__(256) void final_dot(const float* __restrict__ h,
                                                 const float* __restrict__ Wc,
                                                 const float* __restrict__ bc,
                                                 float* __restrict__ out, int n) {
  int wid = (blockIdx.x * blockDim.x + threadIdx.x) >> 6;
  int lane = threadIdx.x & 63;
  if (wid >= n) return;
  float2 w = ((const float2*)Wc)[lane];
  float2 v = ((const float2*)&h[(size_t)wid * 128])[lane];
  float s = v.x * w.x + v.y * w.y;
#pragma unroll
  for (int off = 32; off; off >>= 1) s += __shfl_down(s, off);
  if (lane == 0) out[wid] = s + bc[0];
}

// ---------------- launch ----------------

extern "C" void kernel_launch(void* const* d_in, const int* in_sizes, int n_in,
                              void* d_out, int out_size, void* d_ws, size_t ws_size,
                              hipStream_t stream) {
  const float* x  = (const float*)d_in[0];
  const int* ei   = (const int*)d_in[1];
  const float* W1 = (const float*)d_in[2];
  const float* b1 = (const float*)d_in[3];
  const float* W2 = (const float*)d_in[4];
  const float* b2 = (const float*)d_in[5];
  const float* Wc = (const float*)d_in[6];
  const float* bc = (const float*)d_in[7];
  float* out = (float*)d_out;

  int n  = in_sizes[0] / 128;
  int ne = in_sizes[1] / 2;
  const int* src = ei;
  const int* dst = ei + ne;

  char* p = (char*)d_ws;
  auto alloc = [&](size_t bytes) {
    char* r = p;
    p += (bytes + 255) & ~(size_t)255;
    return r;
  };
  int*   cnt     = (int*)alloc((size_t)n * 4);
  int*   part    = (int*)alloc((size_t)n * 4);
  int*   bsum    = (int*)alloc(64 * 4);
  int*   row_ptr = (int*)alloc((size_t)(n + 1) * 4);
  int*   cursor  = (int*)alloc((size_t)n * 4);
  int*   col     = (int*)alloc((size_t)ne * 4);
  float* dinv    = (float*)alloc((size_t)n * 4);
  float* hs      = (float*)alloc((size_t)n * 128 * 4);
  float* hbuf    = (float*)alloc((size_t)n * 128 * 4);

  hipMemsetAsync(cnt, 0, (size_t)n * 4, stream);
  count_edges<<<(ne + 255) / 256, 256, 0, stream>>>(dst, cnt, ne);
  compute_dinv<<<(n + 255) / 256, 256, 0, stream>>>(cnt, dinv, n);
  int nsb = (n + 1023) / 1024;  // 49 for n=50000, must be <= 64
  scan_block<<<nsb, 1024, 0, stream>>>(cnt, part, bsum, n);
  scan_bsum<<<1, 64, 0, stream>>>(bsum, nsb);
  finalize_rowptr<<<(n + 1 + 255) / 256, 256, 0, stream>>>(part, bsum, row_ptr, n, ne);
  hipMemcpyAsync(cursor, row_ptr, (size_t)n * 4, hipMemcpyDeviceToDevice, stream);
  fill_csr<<<(ne + 255) / 256, 256, 0, stream>>>(src, dst, cursor, col, ne);

  int gemm_blocks = (n + 63) / 64;
  int agg_blocks = (n + 3) / 4;  // 4 waves/block, 1 wave/node

  gemm_scale<<<gemm_blocks, 256, 0, stream>>>(x, W1, dinv, hs, n);
  aggregate<<<agg_blocks, 256, 0, stream>>>(hs, row_ptr, col, dinv, b1, hbuf, n);
  gemm_scale<<<gemm_blocks, 256, 0, stream>>>(hbuf, W2, dinv, hs, n);
  aggregate<<<agg_blocks, 256, 0, stream>>>(hs, row_ptr, col, dinv, b2, hbuf, n);
  final_dot<<<agg_blocks, 256, 0, stream>>>(hbuf, Wc, bc, out, n);
}

// Round 2
// 382.586 us; speedup vs baseline: 1.2738x; 1.2738x over previous
//
#include <hip/hip_runtime.h>
#include <cstdint>

// ---------------- CSR build ----------------
// Pass A: degree count + per-edge rank (the only atomic pass).
// packed[e] = (rank << 16) | dst   (dst < 65536, rank < 65536 for this graph)

__global__ void count_rank(const int* __restrict__ dst, int* __restrict__ cnt,
                           uint32_t* __restrict__ packed, int ne) {
  int e = blockIdx.x * blockDim.x + threadIdx.x;
  if (e < ne) {
    int d = dst[e];
    int r = atomicAdd(&cnt[d], 1);
    packed[e] = ((uint32_t)r << 16) | (uint32_t)d;
  }
}

__global__ void compute_dinv(const int* __restrict__ cnt, float* __restrict__ dinv, int n) {
  int i = blockIdx.x * blockDim.x + threadIdx.x;
  if (i < n) dinv[i] = rsqrtf((float)(cnt[i] + 1));  // +1 self-loop; always > 0
}

__global__ void scan_block(const int* __restrict__ cnt, int* __restrict__ part,
                           int* __restrict__ bsum, int n) {
  __shared__ int s[1024];
  int i = blockIdx.x * 1024 + threadIdx.x;
  int v = (i < n) ? cnt[i] : 0;
  s[threadIdx.x] = v;
  __syncthreads();
  for (int off = 1; off < 1024; off <<= 1) {
    int t = (threadIdx.x >= (unsigned)off) ? s[threadIdx.x - off] : 0;
    __syncthreads();
    s[threadIdx.x] += t;
    __syncthreads();
  }
  if (i < n) part[i] = s[threadIdx.x] - v;           // exclusive within block
  if (threadIdx.x == 1023) bsum[blockIdx.x] = s[1023];
}

__global__ void scan_bsum(int* __restrict__ bsum, int nb) {  // nb <= 64
  int lane = threadIdx.x;
  int v = (lane < nb) ? bsum[lane] : 0;
  int orig = v;
  for (int off = 1; off < 64; off <<= 1) {
    int t = __shfl_up(v, off);
    if (lane >= off) v += t;
  }
  if (lane < nb) bsum[lane] = v - orig;              // exclusive block offsets
}

__global__ void finalize_rowptr(const int* __restrict__ part, const int* __restrict__ bsum,
                                int* __restrict__ row_ptr, int n, int total) {
  int i = blockIdx.x * blockDim.x + threadIdx.x;
  if (i < n) row_ptr[i] = part[i] + bsum[i >> 10];
  if (i == n) row_ptr[n] = total;
}

// Pass B: atomic-free scatter, XCD-range-localized.
// Grid = nchunks * NSEG blocks; block b: edge chunk b/NSEG, dst-range b%NSEG.
// With round-robin block->XCD mapping, each XCD writes only its ~(ne/NSEG*4)B
// slice of col, so dirty lines coalesce in that XCD's L2 (one writeback).
// Every edge is written by exactly one (chunk,range) block -> correct w/o
// any mapping assumption; the mapping only affects locality.

#define SCAT_EPB 2048  // edges per block (256 thr x 8)

__global__ __launch_bounds__(256) void scatter_csr(const int* __restrict__ src,
                                                   const uint32_t* __restrict__ packed,
                                                   const int* __restrict__ row_ptr,
                                                   int* __restrict__ col,
                                                   int ne, int nseg, int seg_size) {
  int range = blockIdx.x % nseg;
  int chunk = blockIdx.x / nseg;
  int lo = range * seg_size;
  int hi = lo + seg_size;
  int base = chunk * SCAT_EPB;
#pragma unroll
  for (int j = 0; j < 8; ++j) {
    int e = base + j * 256 + threadIdx.x;
    if (e < ne) {
      uint32_t pk = packed[e];
      int d = (int)(pk & 0xFFFFu);
      if (d >= lo && d < hi) {
        int pos = row_ptr[d] + (int)(pk >> 16);
        col[pos] = src[e];
      }
    }
  }
}

// ---------------- GEMM (fp32, 128-wide weights) fused with dinv pre-scale ----------------

__global__ __launch_bounds__(256) void gemm_scale(const float* __restrict__ in,
                                                  const float* __restrict__ W,
                                                  const float* __restrict__ dinv,
                                                  float* __restrict__ out, int nrows) {
  __shared__ float ws[16][128];
  __shared__ float xs[64][17];
  int row0 = blockIdx.x * 64;
  int tid = threadIdx.x;
  int rg = tid >> 4;   // 0..15 -> rows rg*4..rg*4+3
  int cg = tid & 15;   // 0..15 -> cols cg*4 & 64+cg*4

  float acc[4][8] = {{0.f}};

  for (int k0 = 0; k0 < 128; k0 += 16) {
    {
      int idx = tid * 8;
      int kk = idx >> 7;
      int f = idx & 127;
      float4 a = *(const float4*)&W[(size_t)(k0 + kk) * 128 + f];
      float4 b = *(const float4*)&W[(size_t)(k0 + kk) * 128 + f + 4];
      *(float4*)&ws[kk][f] = a;
      *(float4*)&ws[kk][f + 4] = b;
    }
    {
      int idx = tid * 4;
      int r = idx >> 4;
      int kk = idx & 15;
      int grow = row0 + r;
      float4 v = make_float4(0.f, 0.f, 0.f, 0.f);
      if (grow < nrows) v = *(const float4*)&in[(size_t)grow * 128 + k0 + kk];
      xs[r][kk] = v.x; xs[r][kk + 1] = v.y; xs[r][kk + 2] = v.z; xs[r][kk + 3] = v.w;
    }
    __syncthreads();
#pragma unroll
    for (int kk = 0; kk < 16; ++kk) {
      float b0[8];
      *(float4*)&b0[0] = *(const float4*)&ws[kk][cg * 4];
      *(float4*)&b0[4] = *(const float4*)&ws[kk][64 + cg * 4];
      float a0 = xs[rg * 4 + 0][kk];
      float a1 = xs[rg * 4 + 1][kk];
      float a2 = xs[rg * 4 + 2][kk];
      float a3 = xs[rg * 4 + 3][kk];
#pragma unroll
      for (int j = 0; j < 8; ++j) {
        acc[0][j] += a0 * b0[j];
        acc[1][j] += a1 * b0[j];
        acc[2][j] += a2 * b0[j];
        acc[3][j] += a3 * b0[j];
      }
    }
    __syncthreads();
  }

#pragma unroll
  for (int r = 0; r < 4; ++r) {
    int grow = row0 + rg * 4 + r;
    if (grow < nrows) {
      float s = dinv[grow];
      float4 o0 = make_float4(acc[r][0] * s, acc[r][1] * s, acc[r][2] * s, acc[r][3] * s);
      float4 o1 = make_float4(acc[r][4] * s, acc[r][5] * s, acc[r][6] * s, acc[r][7] * s);
      *(float4*)&out[(size_t)grow * 128 + cg * 4] = o0;
      *(float4*)&out[(size_t)grow * 128 + 64 + cg * 4] = o1;
    }
  }
}

// ---------------- Aggregation (gather over CSR) + post-scale + bias + relu ----------------

__global__ __launch_bounds__(256) void aggregate(const float* __restrict__ hs,
                                                 const int* __restrict__ row_ptr,
                                                 const int* __restrict__ col,
                                                 const float* __restrict__ dinv,
                                                 const float* __restrict__ bias,
                                                 float* __restrict__ out, int n) {
  int wid = (blockIdx.x * blockDim.x + threadIdx.x) >> 6;
  int lane = threadIdx.x & 63;
  if (wid >= n) return;
  int i = wid;
  int start = row_ptr[i];
  int end = row_ptr[i + 1];

  float2 acc = ((const float2*)&hs[(size_t)i * 128])[lane];  // self-loop term

  int e = start;
  for (; e + 4 <= end; e += 4) {
    int s0 = col[e + 0];
    int s1 = col[e + 1];
    int s2 = col[e + 2];
    int s3 = col[e + 3];
    float2 v0 = ((const float2*)&hs[(size_t)s0 * 128])[lane];
    float2 v1 = ((const float2*)&hs[(size_t)s1 * 128])[lane];
    float2 v2 = ((const float2*)&hs[(size_t)s2 * 128])[lane];
    float2 v3 = ((const float2*)&hs[(size_t)s3 * 128])[lane];
    acc.x += (v0.x + v1.x) + (v2.x + v3.x);
    acc.y += (v0.y + v1.y) + (v2.y + v3.y);
  }
  for (; e < end; ++e) {
    int s0 = col[e];
    float2 v0 = ((const float2*)&hs[(size_t)s0 * 128])[lane];
    acc.x += v0.x;
    acc.y += v0.y;
  }

  float d = dinv[i];
  float2 b = ((const float2*)bias)[lane];
  float ox = fmaxf(acc.x * d + b.x, 0.f);
  float oy = fmaxf(acc.y * d + b.y, 0.f);
  ((float2*)&out[(size_t)i * 128])[lane] = make_float2(ox, oy);
}

// ---------------- Aggregation fused with final 128->1 projection ----------------
// out[i] = dot(relu(agg_i * dinv[i] + b2), Wc) + bc

__global__ __launch_bounds__(256) void aggregate_dot(const float* __restrict__ hs,
                                                     const int* __restrict__ row_ptr,
                                                     const int* __restrict__ col,
                                                     const float* __restrict__ dinv,
                                                     const float* __restrict__ bias,
                                                     const float* __restrict__ Wc,
                                                     const float* __restrict__ bc,
                                                     float* __restrict__ out, int n) {
  int wid = (blockIdx.x * blockDim.x + threadIdx.x) >> 6;
  int lane = threadIdx.x & 63;
  if (wid >= n) return;
  int i = wid;
  int start = row_ptr[i];
  int end = row_ptr[i + 1];

  float2 acc = ((const float2*)&hs[(size_t)i * 128])[lane];  // self-loop term

  int e = start;
  for (; e + 4 <= end; e += 4) {
    int s0 = col[e + 0];
    int s1 = col[e + 1];
    int s2 = col[e + 2];
    int s3 = col[e + 3];
    float2 v0 = ((const float2*)&hs[(size_t)s0 * 128])[lane];
    float2 v1 = ((const float2*)&hs[(size_t)s1 * 128])[lane];
    float2 v2 = ((const float2*)&hs[(size_t)s2 * 128])[lane];
    float2 v3 = ((const float2*)&hs[(size_t)s3 * 128])[lane];
    acc.x += (v0.x + v1.x) + (v2.x + v3.x);
    acc.y += (v0.y + v1.y) + (v2.y + v3.y);
  }
  for (; e < end; ++e) {
    int s0 = col[e];
    float2 v0 = ((const float2*)&hs[(size_t)s0 * 128])[lane];
    acc.x += v0.x;
    acc.y += v0.y;
  }

  float d = dinv[i];
  float2 b = ((const float2*)bias)[lane];
  float2 w = ((const float2*)Wc)[lane];
  float ox = fmaxf(acc.x * d + b.x, 0.f);
  float oy = fmaxf(acc.y * d + b.y, 0.f);
  float s = ox * w.x + oy * w.y;
#pragma unroll
  for (int off = 32; off; off >>= 1) s += __shfl_down(s, off);
  if (lane == 0) out[i] = s + bc[0];
}

// ---------------- launch ----------------

extern "C" void kernel_launch(void* const* d_in, const int* in_sizes, int n_in,
                              void* d_out, int out_size, void* d_ws, size_t ws_size,
                              hipStream_t stream) {
  const float* x  = (const float*)d_in[0];
  const int* ei   = (const int*)d_in[1];
  const float* W1 = (const float*)d_in[2];
  const float* b1 = (const float*)d_in[3];
  const float* W2 = (const float*)d_in[4];
  const float* b2 = (const float*)d_in[5];
  const float* Wc = (const float*)d_in[6];
  const float* bc = (const float*)d_in[7];
  float* out = (float*)d_out;

  int n  = in_sizes[0] / 128;
  int ne = in_sizes[1] / 2;
  const int* src = ei;
  const int* dst = ei + ne;

  char* p = (char*)d_ws;
  auto alloc = [&](size_t bytes) {
    char* r = p;
    p += (bytes + 255) & ~(size_t)255;
    return r;
  };
  int*   cnt     = (int*)alloc((size_t)n * 4);
  int*   part    = (int*)alloc((size_t)n * 4);
  int*   bsum    = (int*)alloc(64 * 4);
  int*   row_ptr = (int*)alloc((size_t)(n + 1) * 4);
  float* dinv    = (float*)alloc((size_t)n * 4);
  int*   col     = (int*)alloc((size_t)ne * 4);
  float* hs      = (float*)alloc((size_t)n * 128 * 4);
  float* hbuf    = (float*)alloc((size_t)n * 128 * 4);
  // packed aliases hbuf: packed is dead after scatter_csr; hbuf first written
  // by aggregate (layer 1), which runs strictly later on the same stream.
  uint32_t* packed = (uint32_t*)hbuf;

  hipMemsetAsync(cnt, 0, (size_t)n * 4, stream);
  count_rank<<<(ne + 255) / 256, 256, 0, stream>>>(dst, cnt, packed, ne);
  compute_dinv<<<(n + 255) / 256, 256, 0, stream>>>(cnt, dinv, n);
  int nsb = (n + 1023) / 1024;  // 49 for n=50000, must be <= 64
  scan_block<<<nsb, 1024, 0, stream>>>(cnt, part, bsum, n);
  scan_bsum<<<1, 64, 0, stream>>>(bsum, nsb);
  finalize_rowptr<<<(n + 1 + 255) / 256, 256, 0, stream>>>(part, bsum, row_ptr, n, ne);

  const int NSEG = 8;  // one dst-range per XCD
  int seg_size = (n + NSEG - 1) / NSEG;
  int nchunks = (ne + SCAT_EPB - 1) / SCAT_EPB;
  scatter_csr<<<nchunks * NSEG, 256, 0, stream>>>(src, packed, row_ptr, col, ne, NSEG, seg_size);

  int gemm_blocks = (n + 63) / 64;
  int agg_blocks = (n + 3) / 4;  // 4 waves/block, 1 wave/node

  gemm_scale<<<gemm_blocks, 256, 0, stream>>>(x, W1, dinv, hs, n);
  aggregate<<<agg_blocks, 256, 0, stream>>>(hs, row_ptr, col, dinv, b1, hbuf, n);
  gemm_scale<<<gemm_blocks, 256, 0, stream>>>(hbuf, W2, dinv, hs, n);
  aggregate_dot<<<agg_blocks, 256, 0, stream>>>(hs, row_ptr, col, dinv, b2, Wc, bc, out, n);
}